// Round 7
// baseline (96.275 us; speedup 1.0000x reference)
//
#include <hip/hip_runtime.h>

#define DEV __device__ __forceinline__

typedef unsigned short u16;
typedef __attribute__((ext_vector_type(8))) __bf16 bf16x8;
typedef __attribute__((ext_vector_type(4))) float f32x4;
typedef __attribute__((ext_vector_type(8))) unsigned short u16x8;

// Problem constants: B=16, T=4096, Din=Dout=S=256
static constexpr int NCH_TOT = 1024;  // 64-row chunks total (16 batches x 64)

DEV u16 f2bf(float f) {
  unsigned u = __builtin_bit_cast(unsigned, f);
  u += 0x7fffu + ((u >> 16) & 1u);
  return (u16)(u >> 16);
}
DEV float bf2f(u16 h) {
  unsigned u = ((unsigned)h) << 16;
  return __builtin_bit_cast(float, u);
}

DEV void gl_lds16(const void* gp, void* lp) {
  __builtin_amdgcn_global_load_lds(
      (__attribute__((address_space(1))) void*)(void*)gp,
      (__attribute__((address_space(3))) void*)lp, 16, 0, 0);
}

// ---------------- prep: a = tanh(a_raw); b,c,d -> bf16 ----------------
__global__ __launch_bounds__(256) void prep_k(const float* __restrict__ a_raw,
                                              const float* __restrict__ b,
                                              const float* __restrict__ c,
                                              const float* __restrict__ d,
                                              float* __restrict__ af,
                                              u16* __restrict__ bw,
                                              u16* __restrict__ cw,
                                              u16* __restrict__ dw) {
  int i = blockIdx.x * 256 + threadIdx.x;
  if (i < 256) af[i] = tanhf(a_raw[i]);
  bw[i] = f2bf(b[i]);
  cw[i] = f2bf(c[i]);
  dw[i] = f2bf(d[i]);
}

// ---------------- u fp32 -> bf16, 8 elems/thread ----------------
__global__ __launch_bounds__(256) void convu_k(const float* __restrict__ u,
                                               u16* __restrict__ ub) {
  size_t i = ((size_t)blockIdx.x * 256 + threadIdx.x) * 8;
  float4 v0 = *reinterpret_cast<const float4*>(u + i);
  float4 v1 = *reinterpret_cast<const float4*>(u + i + 4);
  u16x8 o;
  o[0] = f2bf(v0.x); o[1] = f2bf(v0.y); o[2] = f2bf(v0.z); o[3] = f2bf(v0.w);
  o[4] = f2bf(v1.x); o[5] = f2bf(v1.y); o[6] = f2bf(v1.z); o[7] = f2bf(v1.w);
  *reinterpret_cast<u16x8*>(ub + i) = o;
}

// ---------------- gemm1: Bu = u @ b^T + per-QUARTER-chunk carries ----------------
// R1-proven shape: 256 thr / 4 waves (2x2), 128x128 tile, BK=64, gl_lds both
// operands, pre-swizzled source (rule 21). bu written in gemm2's tile-local
// quarter-major layout: tile = 64 rows; u16 idx within tile =
//   (s>>6)*4096 + r*64 + (((s>>3)&7 ^ (r&7))*8) + (s&7).
// carry4[chunk][j][s] = sum_{q=0..15} a_s^(15-q) Bu[j*16+q][s]  (j = mi directly).
__global__ __launch_bounds__(256) void gemm1_k(const u16* __restrict__ ubf,
                                               const u16* __restrict__ bw,
                                               const float* __restrict__ af,
                                               u16* __restrict__ bu,
                                               float* __restrict__ carry4) {
  __shared__ u16 As[128 * 64];
  __shared__ u16 Bs[128 * 64];
  const int tid = threadIdx.x;
  const int lane = tid & 63;
  const int wid = tid >> 6;
  const int wm = wid >> 1, wn = wid & 1;
  const int panel = blockIdx.x;
  const size_t row0 = (size_t)blockIdx.y * 128;
  const int col0 = panel * 128;

  const int rstg = tid >> 3;
  const int c16 = tid & 7;

  const f32x4 zero = {0.f, 0.f, 0.f, 0.f};
  f32x4 acc[4][4];
#pragma unroll
  for (int i = 0; i < 4; ++i)
#pragma unroll
    for (int j = 0; j < 4; ++j) acc[i][j] = zero;

#pragma unroll
  for (int kt = 0; kt < 4; ++kt) {
    const int kb = kt * 64;
#pragma unroll
    for (int j = 0; j < 4; ++j) {
      int row = j * 32 + rstg;
      int sc = c16 ^ (row & 7);
      gl_lds16(ubf + (row0 + row) * 256 + kb + sc * 8,
               (char*)As + j * 4096 + wid * 1024);
      gl_lds16(bw + (size_t)(col0 + row) * 256 + kb + sc * 8,
               (char*)Bs + j * 4096 + wid * 1024);
    }
    __syncthreads();
#pragma unroll
    for (int kk = 0; kk < 2; ++kk) {
      const int ks = kk * 4 + (lane >> 4);
      bf16x8 afr[4], bfr[4];
#pragma unroll
      for (int mi = 0; mi < 4; ++mi) {
        int ar = wm * 64 + mi * 16 + (lane & 15);
        afr[mi] = *reinterpret_cast<const bf16x8*>(&As[ar * 64 + (ks ^ (ar & 7)) * 8]);
      }
#pragma unroll
      for (int ni = 0; ni < 4; ++ni) {
        int br = wn * 64 + ni * 16 + (lane & 15);
        bfr[ni] = *reinterpret_cast<const bf16x8*>(&Bs[br * 64 + (ks ^ (br & 7)) * 8]);
      }
#pragma unroll
      for (int mi = 0; mi < 4; ++mi)
#pragma unroll
        for (int ni = 0; ni < 4; ++ni)
          acc[mi][ni] = __builtin_amdgcn_mfma_f32_16x16x32_bf16(
              afr[mi], bfr[ni], acc[mi][ni], 0, 0, 0);
    }
    if (kt < 3) __syncthreads();
  }

  // ---- epilogue: bu in gemm2 tile-local quarter-major layout ----
  const size_t t2 = (size_t)blockIdx.y * 2 + wm;   // 64-row chunk index
#pragma unroll
  for (int mi = 0; mi < 4; ++mi) {
    int rbase = mi * 16 + (lane >> 4) * 4;         // row within chunk (0..63)
#pragma unroll
    for (int ni = 0; ni < 4; ++ni) {
      int col = col0 + wn * 64 + ni * 16 + (lane & 15);
      int colpart = (col >> 6) * 4096 + (col & 7);
      int sl = (col >> 3) & 7;
#pragma unroll
      for (int q = 0; q < 4; ++q) {
        int r = rbase + q;
        bu[t2 * 16384 + colpart + r * 64 + ((sl ^ (r & 7)) * 8)] = f2bf(acc[mi][ni][q]);
      }
    }
  }

  // ---- quarter carries: weight a^(15 - (tb+q)) within each 16-row block mi ----
  {
    const int tb = (lane >> 4) * 4;
#pragma unroll
    for (int ni = 0; ni < 4; ++ni) {
      int col = col0 + wn * 64 + ni * 16 + (lane & 15);
      float a = af[col];
      float c2 = a * a, c4 = c2 * c2, c8 = c4 * c4, a12 = c8 * c4;
      float base = (tb == 0) ? a12 : (tb == 4) ? c8 : (tb == 8) ? c4 : 1.0f;
#pragma unroll
      for (int mi = 0; mi < 4; ++mi) {
        float p = base, sq = 0.f;
#pragma unroll
        for (int q = 3; q >= 0; --q) {
          sq = fmaf(p, acc[mi][ni][q], sq);
          if (q) p *= a;
        }
        sq += __shfl_xor(sq, 16, 64);
        sq += __shfl_xor(sq, 32, 64);
        if ((lane >> 4) == 0) carry4[t2 * 1024 + mi * 256 + col] = sq;
      }
    }
  }
}

// ---------------- scan2: exclusive scan of quarter-carries (a^16 steps) ---------
__global__ __launch_bounds__(256) void scan2_k(const float* __restrict__ carry4,
                                               const float* __restrict__ af,
                                               float* __restrict__ initb4) {
  int b = blockIdx.x;  // 16
  int s = threadIdx.x;
  float a = af[s];
  float a16 = a * a; a16 = a16 * a16; a16 = a16 * a16; a16 = a16 * a16;  // a^16
  float x = 0.f;
  size_t base = (size_t)b * 64 * 1024 + s;
  float c0 = carry4[base], c1 = carry4[base + 256],
        c2 = carry4[base + 512], c3 = carry4[base + 768];
  for (int k = 0; k < 64; ++k) {
    size_t idx = base + (size_t)k * 1024;
    float n0 = 0.f, n1 = 0.f, n2 = 0.f, n3 = 0.f;
    if (k < 63) {
      size_t nx = idx + 1024;
      n0 = carry4[nx]; n1 = carry4[nx + 256]; n2 = carry4[nx + 512]; n3 = carry4[nx + 768];
    }
    initb4[idx] = x;        x = fmaf(a16, x, c0);
    initb4[idx + 256] = x;  x = fmaf(a16, x, c1);
    initb4[idx + 512] = x;  x = fmaf(a16, x, c2);
    initb4[idx + 768] = x;  x = fmaf(a16, x, c3);
    c0 = n0; c1 = n1; c2 = n2; c3 = n3;
  }
}

// ---------------- gemm2: y = xs@c^T + u@d^T, tile 64x128, 3 blocks/CU ----------
// grid (2, 1024): by = 64-row chunk, bx = col half (fastest -> L2 reuse).
// 512 thr, 8 waves (2x4), wave tile 32x32, acc[2][2].
// XS [64][256] quarter-major swizzled bf16 (32KB): holds xs for phase A; each
// quarter is overwritten with the u tile right after its last phase-A read.
// CS [128][64] (16KB): weight K-tiles (c then d). K-loop = 8 steps of 64.
__global__ __launch_bounds__(512, 6) void gemm2_k(const u16* __restrict__ bu,
                                                  const u16* __restrict__ cw,
                                                  const u16* __restrict__ dw,
                                                  const u16* __restrict__ ubf,
                                                  const float* __restrict__ af,
                                                  const float* __restrict__ initb4,
                                                  float* __restrict__ y) {
  __shared__ u16 XS[64 * 256];
  __shared__ u16 CS[128 * 64];
  const int tid = threadIdx.x;
  const int lane = tid & 63;
  const int wid = tid >> 6;
  const int wr = wid >> 2, wc = wid & 3;
  const int by = blockIdx.y;
  const int col0 = blockIdx.x * 128;

  // prologue: bu tile (linear, already in layout) + c k=0
  const char* src = (const char*)bu + (size_t)by * 32768;
#pragma unroll
  for (int j = 0; j < 4; ++j)
    gl_lds16(src + j * 8192 + tid * 16, (char*)XS + j * 8192 + wid * 1024);
#pragma unroll
  for (int rr = 0; rr < 2; ++rr) {
    int brow = rr * 64 + (tid >> 3);
    int sc = (tid & 7) ^ (brow & 7);
    gl_lds16(cw + (size_t)(col0 + brow) * 256 + sc * 8,
             (char*)CS + rr * 8192 + wid * 1024);
  }
  __syncthreads();

  // ---- recon: 2 independent 16-step chains per thread; reads hoisted ----
  {
    const int s = tid & 255;
    const int pair = tid >> 8;  // 0: rows 0..31, 1: rows 32..63
    const float a = af[s];
    const int colpart = (s >> 6) * 4096 + (s & 7);
    const int sl = (s >> 3) & 7;
    float x1 = initb4[(size_t)by * 1024 + (pair * 2) * 256 + s];
    float x2 = initb4[(size_t)by * 1024 + (pair * 2 + 1) * 256 + s];
    const int rA0 = pair * 32, rB0 = pair * 32 + 16;
    float vA[16], vB[16];
#pragma unroll
    for (int t = 0; t < 16; ++t) {
      int rA = rA0 + t, rB = rB0 + t;
      vA[t] = bf2f(XS[colpart + rA * 64 + ((sl ^ (rA & 7)) * 8)]);
      vB[t] = bf2f(XS[colpart + rB * 64 + ((sl ^ (rB & 7)) * 8)]);
    }
#pragma unroll
    for (int t = 0; t < 16; ++t) {
      x1 = fmaf(a, x1, vA[t]); vA[t] = x1;
      x2 = fmaf(a, x2, vB[t]); vB[t] = x2;
    }
#pragma unroll
    for (int t = 0; t < 16; ++t) {
      int rA = rA0 + t, rB = rB0 + t;
      XS[colpart + rA * 64 + ((sl ^ (rA & 7)) * 8)] = f2bf(vA[t]);
      XS[colpart + rB * 64 + ((sl ^ (rB & 7)) * 8)] = f2bf(vB[t]);
    }
  }
  __syncthreads();

  f32x4 acc[2][2];
  const f32x4 zero = {0.f, 0.f, 0.f, 0.f};
  acc[0][0] = zero; acc[0][1] = zero; acc[1][0] = zero; acc[1][1] = zero;

  // ---- K loop: steps 0-3 = xs@c^T, steps 4-7 = u@d^T ----
#pragma unroll
  for (int kt8 = 0; kt8 < 8; ++kt8) {
#pragma unroll
    for (int kk = 0; kk < 2; ++kk) {
      const int ksl = kk * 4 + (lane >> 4);
      bf16x8 afr[2], bfr[2];
#pragma unroll
      for (int mi = 0; mi < 2; ++mi) {
        int ar = wr * 32 + mi * 16 + (lane & 15);
        afr[mi] = *reinterpret_cast<const bf16x8*>(
            &XS[(kt8 & 3) * 4096 + ar * 64 + ((ksl ^ (ar & 7)) * 8)]);
      }
#pragma unroll
      for (int ni = 0; ni < 2; ++ni) {
        int nr = wc * 32 + ni * 16 + (lane & 15);
        bfr[ni] = *reinterpret_cast<const bf16x8*>(&CS[nr * 64 + ((ksl ^ (nr & 7)) * 8)]);
      }
#pragma unroll
      for (int mi = 0; mi < 2; ++mi)
#pragma unroll
        for (int ni = 0; ni < 2; ++ni)
          acc[mi][ni] = __builtin_amdgcn_mfma_f32_16x16x32_bf16(
              afr[mi], bfr[ni], acc[mi][ni], 0, 0, 0);
    }
    if (kt8 < 7) {
      __syncthreads();  // all reads of XS quarter kt8 / CS done
      if (kt8 < 4) {
        // overwrite consumed xs quarter with u tile for phase B
        int r = tid >> 3, cs = tid & 7;
        gl_lds16(ubf + ((size_t)by * 64 + r) * 256 + kt8 * 64 + ((cs ^ (r & 7)) * 8),
                 (char*)XS + kt8 * 8192 + wid * 1024);
      }
      const u16* Wn = (kt8 < 3) ? cw : dw;
      const int kb = (kt8 < 3) ? (kt8 + 1) * 64 : (kt8 - 3) * 64;
#pragma unroll
      for (int rr = 0; rr < 2; ++rr) {
        int brow = rr * 64 + (tid >> 3);
        int sc = (tid & 7) ^ (brow & 7);
        gl_lds16(Wn + (size_t)(col0 + brow) * 256 + kb + sc * 8,
                 (char*)CS + rr * 8192 + wid * 1024);
      }
      __syncthreads();  // staged (vmcnt drained by compiler)
    }
  }

  // ---- epilogue ----
#pragma unroll
  for (int mi = 0; mi < 2; ++mi) {
    int rlb = wr * 32 + mi * 16 + (lane >> 4) * 4;
#pragma unroll
    for (int ni = 0; ni < 2; ++ni) {
      int col = col0 + wc * 32 + ni * 16 + (lane & 15);
#pragma unroll
      for (int q = 0; q < 4; ++q)
        y[((size_t)by * 64 + rlb + q) * 256 + col] = acc[mi][ni][q];
    }
  }
}

extern "C" void kernel_launch(void* const* d_in, const int* in_sizes, int n_in,
                              void* d_out, int out_size, void* d_ws, size_t ws_size,
                              hipStream_t stream) {
  const float* u = (const float*)d_in[0];
  const float* a_raw = (const float*)d_in[1];
  const float* b = (const float*)d_in[2];
  const float* c = (const float*)d_in[3];
  const float* d = (const float*)d_in[4];
  float* y = (float*)d_out;
  char* ws = (char*)d_ws;

  const size_t MB = 1u << 20;
  float* af = (float*)(ws);                       // 1 KB
  u16* bw = (u16*)(ws + 4096);                    // 128 KB
  u16* cw = (u16*)(ws + 4096 + 131072);           // 128 KB
  u16* dw = (u16*)(ws + 4096 + 2 * 131072);       // 128 KB
  u16* ubf = (u16*)(ws + 1 * MB);                 // 32 MB
  u16* bu = (u16*)(ws + 33 * MB);                 // 32 MB (tile quarter-major)
  float* carry4 = (float*)(ws + 65 * MB);         // 4 MB
  float* initb4 = (float*)(ws + 69 * MB);         // 4 MB

  prep_k<<<256, 256, 0, stream>>>(a_raw, b, c, d, af, bw, cw, dw);
  convu_k<<<8192, 256, 0, stream>>>(u, ubf);
  gemm1_k<<<dim3(2, 512), 256, 0, stream>>>(ubf, bw, af, bu, carry4);
  scan2_k<<<16, 256, 0, stream>>>(carry4, af, initb4);
  gemm2_k<<<dim3(2, 1024), 512, 0, stream>>>(bu, cw, dw, ubf, af, initb4, y);
}